// Round 1
// baseline (626.991 us; speedup 1.0000x reference)
//
#include <hip/hip_runtime.h>
#include <hip/hip_bf16.h>

#define N_NODES 100000
#define N_EDGES 640000
#define NODE_D 128
#define MSG_D 128

typedef __bf16 bf16_t;
typedef __bf16 bf16x8 __attribute__((ext_vector_type(8)));
typedef float f32x4 __attribute__((ext_vector_type(4)));

// ---------------------------------------------------------------------------
// Prep: transpose + convert weights to bf16.
//   WtAB [256][384]: rows 0..127 = W_msg columns, rows 128..255 = W_rev columns
//   WtU  [128][128]: WtU[n][k] = W_upd[k][n]
// ---------------------------------------------------------------------------
__global__ void prep_weights_kernel(const float* __restrict__ Wmsg,
                                    const float* __restrict__ Wrev,
                                    const float* __restrict__ Wupd,
                                    bf16_t* __restrict__ WtAB,
                                    bf16_t* __restrict__ WtU) {
    int idx = blockIdx.x * 256 + threadIdx.x;
    if (idx < 256 * 384) {
        int n = idx / 384;
        int k = idx - n * 384;
        float v = (n < 128) ? Wmsg[k * 128 + n] : Wrev[k * 128 + (n - 128)];
        WtAB[idx] = (bf16_t)v;
    }
    if (idx < 128 * 128) {
        int n = idx / 128;
        int k = idx - n * 128;
        WtU[idx] = (bf16_t)Wupd[k * 128 + n];
    }
}

// ---------------------------------------------------------------------------
// Edge kernel: per block of 64 edges:
//   gather [node[from]|node[to]|edge_feat] -> bf16 LDS tile A[64][384] (swizzled)
//   GEMM A @ WtAB^T (N=256: msg||rev) via mfma_f32_16x16x32_bf16
//   messages = relu(msg + b_msg) + relu(rev + b_rev)
//   atomic scatter-add into agg[to_idx]
// Wave wv owns cols [wv*32, wv*32+32) of BOTH msg and rev halves.
// ---------------------------------------------------------------------------
__global__ __launch_bounds__(256, 2)
void edge_msg_kernel(const float* __restrict__ nodef,
                     const float* __restrict__ edgef,
                     const int* __restrict__ from_idx,
                     const int* __restrict__ to_idx,
                     const bf16_t* __restrict__ WtAB,
                     const float* __restrict__ b_msg,
                     const float* __restrict__ b_rev,
                     float* __restrict__ agg) {
    __shared__ char lds_raw[64 * 768];  // A tile: [64 rows][384 cols] bf16, XOR-swizzled

    const int tid = threadIdx.x;
    const int eb = blockIdx.x * 64;

    // ---- stage: 64 rows x 96 float4 = 6144 float4 loads, 24 per thread ----
#pragma unroll
    for (int j = 0; j < 24; ++j) {
        int linear = tid + 256 * j;
        int r = linear / 96;
        int q = linear - r * 96;
        int e = eb + r;
        const float* src;
        if (q < 32) {
            src = nodef + (size_t)from_idx[e] * 128 + q * 4;
        } else if (q < 64) {
            src = nodef + (size_t)to_idx[e] * 128 + (q - 32) * 4;
        } else {
            src = edgef + (size_t)e * 128 + (q - 64) * 4;
        }
        float4 v = *reinterpret_cast<const float4*>(src);
        union { bf16_t b[4]; uint2 u; } pk;
        pk.b[0] = (bf16_t)v.x; pk.b[1] = (bf16_t)v.y;
        pk.b[2] = (bf16_t)v.z; pk.b[3] = (bf16_t)v.w;
        int byte = (r * 768 + q * 8) ^ ((r & 7) << 4);
        *reinterpret_cast<uint2*>(lds_raw + byte) = pk.u;
    }
    __syncthreads();

    const int wv = tid >> 6;
    const int lane = tid & 63;
    const int lhi = lane >> 4;   // 0..3
    const int llo = lane & 15;   // 0..15

    f32x4 acc[4][4];
#pragma unroll
    for (int m = 0; m < 4; ++m)
#pragma unroll
        for (int n = 0; n < 4; ++n)
            acc[m][n] = (f32x4){0.f, 0.f, 0.f, 0.f};

    // B pointers: n=0,1 -> msg cols wv*32+16n ; n=2,3 -> rev cols (+128)
    const bf16_t* bptr[4];
#pragma unroll
    for (int n = 0; n < 4; ++n) {
        int colb = (n < 2) ? (wv * 32 + 16 * n) : (128 + wv * 32 + 16 * (n - 2));
        bptr[n] = WtAB + (size_t)(colb + llo) * 384 + lhi * 8;
    }

    // ---- K loop: 384 = 12 x 32 ----
#pragma unroll
    for (int k0 = 0; k0 < 12; ++k0) {
        bf16x8 a[4], b[4];
#pragma unroll
        for (int m = 0; m < 4; ++m) {
            int ra = 16 * m + llo;
            int byte = (ra * 768 + (k0 * 32 + lhi * 8) * 2) ^ ((ra & 7) << 4);
            a[m] = *reinterpret_cast<const bf16x8*>(lds_raw + byte);
        }
#pragma unroll
        for (int n = 0; n < 4; ++n)
            b[n] = *reinterpret_cast<const bf16x8*>(bptr[n] + k0 * 32);
#pragma unroll
        for (int m = 0; m < 4; ++m)
#pragma unroll
            for (int n = 0; n < 4; ++n)
                acc[m][n] = __builtin_amdgcn_mfma_f32_16x16x32_bf16(a[m], b[n], acc[m][n], 0, 0, 0);
    }

    // ---- epilogue: relu-sum both nets, atomic scatter ----
#pragma unroll
    for (int m = 0; m < 4; ++m) {
        int rbase = 16 * m + lhi * 4;
#pragma unroll
        for (int r = 0; r < 4; ++r) {
            int e = eb + rbase + r;
            int dst = to_idx[e];
#pragma unroll
            for (int n = 0; n < 2; ++n) {
                int c = wv * 32 + 16 * n + llo;
                float v = fmaxf(acc[m][n][r] + b_msg[c], 0.f)
                        + fmaxf(acc[m][n + 2][r] + b_rev[c], 0.f);
                unsafeAtomicAdd(&agg[(size_t)dst * 128 + c], v);
            }
        }
    }
}

// ---------------------------------------------------------------------------
// Node update: out = node + relu(agg @ W_upd + b_upd)
// Same MFMA structure, K=128, N=128, BM=64 nodes/block.
// ---------------------------------------------------------------------------
__global__ __launch_bounds__(256, 2)
void node_upd_kernel(const float* __restrict__ agg,
                     const float* __restrict__ nodef,
                     const bf16_t* __restrict__ WtU,
                     const float* __restrict__ b_upd,
                     float* __restrict__ out) {
    __shared__ char lds_raw[64 * 256];  // [64][128] bf16, swizzled

    const int tid = threadIdx.x;
    const int nb = blockIdx.x * 64;

#pragma unroll
    for (int j = 0; j < 8; ++j) {
        int linear = tid + 256 * j;   // 64 rows x 32 float4
        int r = linear / 32;
        int q = linear - r * 32;
        int i = nb + r;
        float4 v = make_float4(0.f, 0.f, 0.f, 0.f);
        if (i < N_NODES)
            v = *reinterpret_cast<const float4*>(agg + (size_t)i * 128 + q * 4);
        union { bf16_t b[4]; uint2 u; } pk;
        pk.b[0] = (bf16_t)v.x; pk.b[1] = (bf16_t)v.y;
        pk.b[2] = (bf16_t)v.z; pk.b[3] = (bf16_t)v.w;
        int byte = (r * 256 + q * 8) ^ ((r & 7) << 4);
        *reinterpret_cast<uint2*>(lds_raw + byte) = pk.u;
    }
    __syncthreads();

    const int wv = tid >> 6;
    const int lane = tid & 63;
    const int lhi = lane >> 4;
    const int llo = lane & 15;

    f32x4 acc[4][2];
#pragma unroll
    for (int m = 0; m < 4; ++m)
#pragma unroll
        for (int n = 0; n < 2; ++n)
            acc[m][n] = (f32x4){0.f, 0.f, 0.f, 0.f};

#pragma unroll
    for (int k0 = 0; k0 < 4; ++k0) {
        bf16x8 a[4], b[2];
#pragma unroll
        for (int m = 0; m < 4; ++m) {
            int ra = 16 * m + llo;
            int byte = (ra * 256 + (k0 * 32 + lhi * 8) * 2) ^ ((ra & 7) << 4);
            a[m] = *reinterpret_cast<const bf16x8*>(lds_raw + byte);
        }
#pragma unroll
        for (int n = 0; n < 2; ++n) {
            int col = wv * 32 + 16 * n + llo;
            b[n] = *reinterpret_cast<const bf16x8*>(WtU + (size_t)col * 128 + k0 * 32 + lhi * 8);
        }
#pragma unroll
        for (int m = 0; m < 4; ++m)
#pragma unroll
            for (int n = 0; n < 2; ++n)
                acc[m][n] = __builtin_amdgcn_mfma_f32_16x16x32_bf16(a[m], b[n], acc[m][n], 0, 0, 0);
    }

#pragma unroll
    for (int m = 0; m < 4; ++m) {
        int rbase = 16 * m + lhi * 4;
#pragma unroll
        for (int r = 0; r < 4; ++r) {
            int i = nb + rbase + r;
            if (i < N_NODES) {
#pragma unroll
                for (int n = 0; n < 2; ++n) {
                    int c = wv * 32 + 16 * n + llo;
                    out[(size_t)i * 128 + c] =
                        nodef[(size_t)i * 128 + c]
                        + fmaxf(acc[m][n][r] + b_upd[c], 0.f);
                }
            }
        }
    }
}

// ---------------------------------------------------------------------------
extern "C" void kernel_launch(void* const* d_in, const int* in_sizes, int n_in,
                              void* d_out, int out_size, void* d_ws, size_t ws_size,
                              hipStream_t stream) {
    const float* nodef    = (const float*)d_in[0];
    const float* edgef    = (const float*)d_in[1];
    const int*   from_idx = (const int*)d_in[2];
    const int*   to_idx   = (const int*)d_in[3];
    const float* Wmsg     = (const float*)d_in[4];
    const float* bmsg     = (const float*)d_in[5];
    const float* Wrev     = (const float*)d_in[6];
    const float* brev     = (const float*)d_in[7];
    const float* Wupd     = (const float*)d_in[8];
    const float* bupd     = (const float*)d_in[9];
    float* out = (float*)d_out;

    char* ws = (char*)d_ws;
    float*  agg  = (float*)ws;                                  // 51,200,000 B
    bf16_t* WtAB = (bf16_t*)(ws + 51200000);                    // 196,608 B
    bf16_t* WtU  = (bf16_t*)(ws + 51200000 + 196608);           // 32,768 B

    hipMemsetAsync(agg, 0, (size_t)N_NODES * MSG_D * sizeof(float), stream);
    prep_weights_kernel<<<384, 256, 0, stream>>>(Wmsg, Wrev, Wupd, WtAB, WtU);
    edge_msg_kernel<<<N_EDGES / 64, 256, 0, stream>>>(
        nodef, edgef, from_idx, to_idx, WtAB, bmsg, brev, agg);
    node_upd_kernel<<<(N_NODES + 63) / 64, 256, 0, stream>>>(
        agg, nodef, WtU, bupd, out);
}